// Round 7
// baseline (495.013 us; speedup 1.0000x reference)
//
#include <hip/hip_runtime.h>
#include <math.h>

#define NPTS 6144
#define CH   128

typedef __attribute__((ext_vector_type(8))) short short8;
typedef __attribute__((ext_vector_type(4))) float f32x4;
typedef __attribute__((ext_vector_type(2))) float f32x2;
typedef __attribute__((ext_vector_type(4))) int   i32x4;

__device__ inline ushort f2bf(float f) {
  union { float f; unsigned u; } v; v.f = f;
  unsigned u = v.u;
  u += 0x7fff + ((u >> 16) & 1);   // round-to-nearest-even
  return (ushort)(u >> 16);
}

__device__ inline f32x2 splat2(float x) { return (f32x2){x, x}; }

__device__ inline float fsqrt(float x) {
  float r; asm("v_sqrt_f32 %0, %1" : "=v"(r) : "v"(x)); return r;
}
__device__ inline float fexp2(float x) {
  float r; asm("v_exp_f32 %0, %1" : "=v"(r) : "v"(x)); return r;
}

// async global->LDS DMA, 16B per lane; LDS dest = wave-uniform base + lane*16
__device__ inline void gload16(const void* g, void* l) {
  __builtin_amdgcn_global_load_lds(
      (const __attribute__((address_space(1))) unsigned int*)g,
      (__attribute__((address_space(3))) unsigned int*)l, 16, 0, 0);
}

// ---------------------------------------------------------------------------
// Kernel 1: embedding  feat = [corr_feat, centered(kp)] @ W_in + b_in
// ---------------------------------------------------------------------------
__global__ __launch_bounds__(128) void k_embed(
    const float* __restrict__ refp, const float* __restrict__ srcp,
    const float* __restrict__ cf, const float* __restrict__ Win,
    const float* __restrict__ bin, float* __restrict__ out) {
  const int row = blockIdx.x, j = threadIdx.x;
  __shared__ float inb[12];
  __shared__ float mkp;
  if (j < 6)       inb[j] = cf[row * 6 + j];
  else if (j < 9)  inb[j] = refp[row * 3 + (j - 6)];
  else if (j < 12) inb[j] = srcp[row * 3 + (j - 9)];
  __syncthreads();
  if (j == 0) {
    float s = inb[6] + inb[7] + inb[8] + inb[9] + inb[10] + inb[11];
    mkp = s * (1.0f / 6.0f);
  }
  __syncthreads();
  float acc = bin[j];
  #pragma unroll
  for (int kk = 0; kk < 12; kk++) {
    float x = inb[kk] - (kk >= 6 ? mkp : 0.0f);
    acc = fmaf(x, Win[kk * CH + j], acc);
  }
  out[row * CH + j] = acc;
}

// ---------------------------------------------------------------------------
// Kernel 2: fused UnaryBlock (linear+LN+leaky) + QKV projection.
// Writes T (mlp output, residual for out-proj), bf16 Q (pre-scaled by
// log2e/sqrt(C)), K row-major, V transposed AND chunk-permuted so the attn
// kernel can DMA contiguous 16B chunks.
// Permutation: key k (within 64-tile) -> pos 32a+8b+4h+lo where
// a=(k>>5)&1, h=(k>>4)&1, b=(k>>2)&3, lo=k&3.
// ---------------------------------------------------------------------------
__global__ __launch_bounds__(128) void k_mlp_qkv(
    const float* __restrict__ X, const float* __restrict__ W,
    const float* __restrict__ b, const float* __restrict__ g,
    const float* __restrict__ beta,
    const float* __restrict__ Wq, const float* __restrict__ bq,
    const float* __restrict__ Wk, const float* __restrict__ bk,
    const float* __restrict__ Wv, const float* __restrict__ bv,
    float* __restrict__ T, ushort* __restrict__ Q, ushort* __restrict__ K,
    ushort* __restrict__ Vt) {
  const int j = threadIdx.x;
  const int r0 = blockIdx.x * 4;
  __shared__ float xs[4][CH];
  __shared__ float hs[4][CH];
  __shared__ float red[2][4];
  #pragma unroll
  for (int r = 0; r < 4; r++) xs[r][j] = X[(r0 + r) * CH + j];
  __syncthreads();

  // ---- phase 1: h = leaky(LN(x @ W + b)) ----
  float acc[4];
  const float bj = b[j];
  #pragma unroll
  for (int r = 0; r < 4; r++) acc[r] = bj;
  for (int kk = 0; kk < CH; kk++) {
    float wv_ = W[kk * CH + j];
    #pragma unroll
    for (int r = 0; r < 4; r++) acc[r] = fmaf(xs[r][kk], wv_, acc[r]);
  }
  const int wv2 = j >> 6, ln = j & 63;
  float sum[4];
  #pragma unroll
  for (int r = 0; r < 4; r++) sum[r] = acc[r];
  #pragma unroll
  for (int o = 32; o; o >>= 1) {
    #pragma unroll
    for (int r = 0; r < 4; r++) sum[r] += __shfl_xor(sum[r], o);
  }
  if (ln == 0) {
    #pragma unroll
    for (int r = 0; r < 4; r++) red[wv2][r] = sum[r];
  }
  __syncthreads();
  float dv[4];
  #pragma unroll
  for (int r = 0; r < 4; r++) {
    float mean = (red[0][r] + red[1][r]) * (1.0f / 128.0f);
    dv[r] = acc[r] - mean;
    sum[r] = dv[r] * dv[r];
  }
  #pragma unroll
  for (int o = 32; o; o >>= 1) {
    #pragma unroll
    for (int r = 0; r < 4; r++) sum[r] += __shfl_xor(sum[r], o);
  }
  __syncthreads();
  if (ln == 0) {
    #pragma unroll
    for (int r = 0; r < 4; r++) red[wv2][r] = sum[r];
  }
  __syncthreads();
  const float gj = g[j], betaj = beta[j];
  #pragma unroll
  for (int r = 0; r < 4; r++) {
    float var = (red[0][r] + red[1][r]) * (1.0f / 128.0f);
    float y = dv[r] * rsqrtf(var + 1e-5f) * gj + betaj;
    y = (y > 0.0f) ? y : 0.1f * y;
    T[(r0 + r) * CH + j] = y;
    hs[r][j] = y;
  }
  __syncthreads();

  // ---- phase 2: Q, K, V from h ----
  float aq[4], ak[4], av[4];
  const float bqj = bq[j], bkj = bk[j], bvj = bv[j];
  #pragma unroll
  for (int r = 0; r < 4; r++) { aq[r] = bqj; ak[r] = bkj; av[r] = bvj; }
  for (int kk = 0; kk < CH; kk++) {
    float wq = Wq[kk * CH + j], wk = Wk[kk * CH + j], wv_ = Wv[kk * CH + j];
    #pragma unroll
    for (int r = 0; r < 4; r++) {
      float x = hs[r][kk];
      aq[r] = fmaf(x, wq, aq[r]);
      ak[r] = fmaf(x, wk, ak[r]);
      av[r] = fmaf(x, wv_, av[r]);
    }
  }
  const float scale = 0.12751879524143007f;  // 1/sqrt(128) * log2(e)
  #pragma unroll
  for (int r = 0; r < 4; r++) {
    Q[(r0 + r) * CH + j] = f2bf(aq[r] * scale);
    K[(r0 + r) * CH + j] = f2bf(ak[r]);
  }
  ushort4 vp;
  vp.x = f2bf(av[0]); vp.y = f2bf(av[1]); vp.z = f2bf(av[2]); vp.w = f2bf(av[3]);
  const int w0 = r0 & 63;
  const int pos = (r0 & ~63) + 32 * ((w0 >> 5) & 1) + 8 * ((w0 >> 2) & 3) +
                  4 * ((w0 >> 4) & 1);
  *(ushort4*)(Vt + (size_t)j * NPTS + pos) = vp;
}

// ---------------------------------------------------------------------------
// Kernel 3: MFMA flash attention, KV-split.
// 512 threads = 8 waves, 128 q-rows/block. global_load_lds staging with
// source-side XOR swizzle (linear LDS dest, swizzle on read). Ks double-
// buffered, Vs single-buffered; 2 barriers/tile; every DMA issued a full
// compute phase before the barrier that drains it. 49.5 KB LDS -> 3 blk/CU.
// ---------------------------------------------------------------------------
__global__ __launch_bounds__(512, 6) void k_attn_mfma(
    const ushort* __restrict__ Q, const ushort* __restrict__ K,
    const ushort* __restrict__ Vt,
    const float* __restrict__ refp, const float* __restrict__ srcp,
    float* __restrict__ Opart, float* __restrict__ ML, int ntiles) {
  const int tid = threadIdx.x;
  const int w = tid >> 6, ln = tid & 63;
  const int l15 = ln & 15, g = ln >> 4;
  const int row0 = blockIdx.x * 128;
  const int seg = blockIdx.y;
  const int t0 = seg * ntiles;

  __shared__ ushort Ks[2][64][128];   // linear; holds chunk c at K-chunk c^(row&7)
  __shared__ ushort Vs[128][64];      // linear; holds chunk c at V-chunk c^(ch&7)
  __shared__ float cs2[6][64];

  // staging source addressing (source pre-swizzled, dest linear)
  const int krow = tid >> 4;                         // 0..31
  const int ksc  = ((tid & 15) ^ (krow & 7)) * 8;    // swizzled source chunk
  const int vch  = tid >> 3;                         // 0..63
  const int vsc  = ((tid & 7) ^ (vch & 7)) * 8;
  char* kdst = (char*)&Ks[0][0][0] + (tid & ~63) * 16;
  char* vdst = (char*)&Vs[0][0] + (tid & ~63) * 16;

  float cr[6];

  f32x4 oacc[8];
  #pragma unroll
  for (int n = 0; n < 8; n++) oacc[n] = (f32x4){0.f, 0.f, 0.f, 0.f};
  float m = -1e30f, l = 0.0f;
  const float invs2 = 1.0f / (0.3f * 0.3f);

  // Q B-fragment
  short8 qf[4];
  {
    const ushort* qp = Q + (size_t)(row0 + 16 * w + l15) * CH + 8 * g;
    #pragma unroll
    for (int ks = 0; ks < 4; ks++) qf[ks] = *(const short8*)(qp + 32 * ks);
  }
  const int qrow = row0 + 16 * w + l15;
  const float rq0 = refp[qrow * 3], rq1 = refp[qrow * 3 + 1], rq2 = refp[qrow * 3 + 2];
  const float sq0 = srcp[qrow * 3], sq1 = srcp[qrow * 3 + 1], sq2 = srcp[qrow * 3 + 2];

  // ---- prologue: coords first (so their wait doesn't drain the DMAs) ----
  if (tid < 64) {
    int gj = t0 * 64 + tid;
    cr[0] = refp[gj * 3]; cr[1] = refp[gj * 3 + 1]; cr[2] = refp[gj * 3 + 2];
    cr[3] = srcp[gj * 3]; cr[4] = srcp[gj * 3 + 1]; cr[5] = srcp[gj * 3 + 2];
  }
  {  // K(t0)->Ks[0], V(t0)->Vs, K(t0+1)->Ks[1]
    const ushort* s0 = K + (size_t)(t0 * 64 + krow) * CH + ksc;
    const ushort* s1 = K + (size_t)(t0 * 64 + krow + 32) * CH + ksc;
    gload16(s0, kdst);
    gload16(s1, kdst + 8192);
    const ushort* v0 = Vt + (size_t)vch * NPTS + t0 * 64 + vsc;
    const ushort* v1 = Vt + (size_t)(vch + 64) * NPTS + t0 * 64 + vsc;
    gload16(v0, vdst);
    gload16(v1, vdst + 8192);
    if (ntiles > 1) {
      const ushort* s2 = K + (size_t)((t0 + 1) * 64 + krow) * CH + ksc;
      const ushort* s3 = K + (size_t)((t0 + 1) * 64 + krow + 32) * CH + ksc;
      gload16(s2, kdst + 16384);
      gload16(s3, kdst + 16384 + 8192);
    }
  }
  if (tid < 64) {
    #pragma unroll
    for (int d = 0; d < 6; d++) cs2[d][tid] = cr[d];
  }
  __syncthreads();

  int cb = 0;
  for (int tt = 0; tt < ntiles; tt++) {
    const int t = t0 + tt;
    // ================= phase A =================
    if (tt > 0) {  // V(t) -> Vs (free since barrier C of t-1); drains at B
      const ushort* v0 = Vt + (size_t)vch * NPTS + t * 64 + vsc;
      const ushort* v1 = Vt + (size_t)(vch + 64) * NPTS + t * 64 + vsc;
      gload16(v0, vdst);
      gload16(v1, vdst + 8192);
    }
    if (tt + 1 < ntiles && tid < 64) {  // coords t+1 (committed at B)
      int gj = (t + 1) * 64 + tid;
      cr[0] = refp[gj * 3]; cr[1] = refp[gj * 3 + 1]; cr[2] = refp[gj * 3 + 2];
      cr[3] = srcp[gj * 3]; cr[4] = srcp[gj * 3 + 1]; cr[5] = srcp[gj * 3 + 2];
    }

    // ---- S^T = K @ Q^T ----
    f32x4 acc[4];
    #pragma unroll
    for (int nb = 0; nb < 4; nb++) acc[nb] = (f32x4){0.f, 0.f, 0.f, 0.f};
    __builtin_amdgcn_s_setprio(1);
    #pragma unroll
    for (int ks = 0; ks < 4; ks++) {
      #pragma unroll
      for (int nb = 0; nb < 4; nb++) {
        const char* src = (const char*)&Ks[cb][0][0] + (16 * nb + l15) * 256 +
                          ((64 * ks + 16 * g) ^ ((l15 & 7) << 4));
        short8 af = *(const short8*)src;
        acc[nb] = __builtin_amdgcn_mfma_f32_16x16x32_bf16(af, qf[ks], acc[nb], 0, 0, 0);
      }
    }
    __builtin_amdgcn_s_setprio(0);

    // ---- geo * S (log2 domain) ----
    float plog[4][4];
    #pragma unroll
    for (int nb = 0; nb < 4; nb++) {
      const int kb = 16 * nb + 4 * g;
      #pragma unroll
      for (int pp = 0; pp < 2; pp++) {
        const int k2 = kb + 2 * pp;
        f32x2 cx = *(const f32x2*)&cs2[0][k2];
        f32x2 cy = *(const f32x2*)&cs2[1][k2];
        f32x2 cz = *(const f32x2*)&cs2[2][k2];
        f32x2 dx = splat2(rq0) - cx, dy = splat2(rq1) - cy, dz = splat2(rq2) - cz;
        f32x2 d2r = dx * dx + dy * dy + dz * dz;
        cx = *(const f32x2*)&cs2[3][k2];
        cy = *(const f32x2*)&cs2[4][k2];
        cz = *(const f32x2*)&cs2[5][k2];
        dx = splat2(sq0) - cx; dy = splat2(sq1) - cy; dz = splat2(sq2) - cz;
        f32x2 d2s = dx * dx + dy * dy + dz * dz;
        f32x2 prod = d2r * d2s;
        f32x2 sum2 = d2r + d2s;
        float s0 = fsqrt(prod[0]), s1 = fsqrt(prod[1]);
        float dd20 = fmaf(-2.0f, s0, sum2[0]);
        float dd21 = fmaf(-2.0f, s1, sum2[1]);
        float gg0 = fmaxf(fmaf(dd20, -invs2, 1.0f), 0.0f);
        float gg1 = fmaxf(fmaf(dd21, -invs2, 1.0f), 0.0f);
        plog[nb][2 * pp]     = gg0 * acc[nb][2 * pp];
        plog[nb][2 * pp + 1] = gg1 * acc[nb][2 * pp + 1];
      }
    }

    // ---- online softmax (defer-rescale) ----
    float tm = fmaxf(fmaxf(plog[0][0], plog[0][1]), fmaxf(plog[0][2], plog[0][3]));
    #pragma unroll
    for (int nb = 1; nb < 4; nb++) {
      float t2 = fmaxf(fmaxf(plog[nb][0], plog[nb][1]),
                       fmaxf(plog[nb][2], plog[nb][3]));
      tm = fmaxf(tm, t2);
    }
    tm = fmaxf(tm, __shfl_xor(tm, 16));
    tm = fmaxf(tm, __shfl_xor(tm, 32));
    if (__any(tm > m + 11.0f)) {
      float nm = fmaxf(m, tm);
      float rsc = fexp2(m - nm);
      l *= rsc;
      #pragma unroll
      for (int n = 0; n < 8; n++) oacc[n] *= rsc;
      m = nm;
    }
    float psum = 0.0f;
    #pragma unroll
    for (int nb = 0; nb < 4; nb++)
      #pragma unroll
      for (int r = 0; r < 4; r++) {
        float p = fexp2(plog[nb][r] - m);
        plog[nb][r] = p;
        psum += p;
      }
    psum += __shfl_xor(psum, 16);
    psum += __shfl_xor(psum, 32);
    l += psum;

    unsigned pk[4][2];
    #pragma unroll
    for (int nb = 0; nb < 4; nb++) {
      asm("v_cvt_pk_bf16_f32 %0, %1, %2"
          : "=v"(pk[nb][0]) : "v"(plog[nb][0]), "v"(plog[nb][1]));
      asm("v_cvt_pk_bf16_f32 %0, %1, %2"
          : "=v"(pk[nb][1]) : "v"(plog[nb][2]), "v"(plog[nb][3]));
    }

    __syncthreads();   // ===== barrier B: Vs(t) ready; Ks[cb] reads done =====

    // ================= phase B =================
    if (tt + 2 < ntiles) {  // K(t+2) -> Ks[cb] (just freed); drains at C
      const ushort* s0 = K + (size_t)((t + 2) * 64 + krow) * CH + ksc;
      const ushort* s1 = K + (size_t)((t + 2) * 64 + krow + 32) * CH + ksc;
      char* d = kdst + cb * 16384;
      gload16(s0, d);
      gload16(s1, d + 8192);
    }

    // ---- O^T += V' @ P^T ----
    union U16 { i32x4 i; short8 s; };
    __builtin_amdgcn_s_setprio(1);
    #pragma unroll
    for (int ks2 = 0; ks2 < 2; ks2++) {
      U16 bfr;
      bfr.i[0] = (int)pk[2 * ks2][0];
      bfr.i[1] = (int)pk[2 * ks2][1];
      bfr.i[2] = (int)pk[2 * ks2 + 1][0];
      bfr.i[3] = (int)pk[2 * ks2 + 1][1];
      #pragma unroll
      for (int nb2 = 0; nb2 < 8; nb2++) {
        const char* vsrc = (const char*)&Vs[0][0] + (16 * nb2 + l15) * 128 +
                           (((4 * ks2 + g) ^ (l15 & 7)) << 4);
        short8 vf = *(const short8*)vsrc;
        oacc[nb2] = __builtin_amdgcn_mfma_f32_16x16x32_bf16(vf, bfr.s, oacc[nb2], 0, 0, 0);
      }
    }
    __builtin_amdgcn_s_setprio(0);

    if (tt + 1 < ntiles && tid < 64) {  // commit coords t+1
      #pragma unroll
      for (int d = 0; d < 6; d++) cs2[d][tid] = cr[d];
    }
    __syncthreads();   // ===== barrier C: Ks[cb](t+2) + cs2 ready; Vs free =====
    cb ^= 1;
  }

  {
    float* op = Opart + ((size_t)seg * NPTS + qrow) * CH;
    #pragma unroll
    for (int nb2 = 0; nb2 < 8; nb2++)
      *(f32x4*)(op + 16 * nb2 + 4 * g) = oacc[nb2];
    if (g == 0) {
      ML[((size_t)seg * NPTS + qrow) * 2]     = m;
      ML[((size_t)seg * NPTS + qrow) * 2 + 1] = l;
    }
  }
}

// ---------------------------------------------------------------------------
// Kernel 4: fused combine(NS partials) + out-proj + residual + LayerNorm.
// ---------------------------------------------------------------------------
__global__ __launch_bounds__(128) void k_out(
    const float* __restrict__ Opart, const float* __restrict__ ML, int NS,
    const float* __restrict__ W, const float* __restrict__ b,
    const float* __restrict__ g, const float* __restrict__ beta,
    const float* __restrict__ res, float* __restrict__ out) {
  const int j = threadIdx.x;
  const int r0 = blockIdx.x * 4;
  __shared__ float xs[4][CH];
  __shared__ float red[2][4];

  // ---- combine phase ----
  #pragma unroll
  for (int r = 0; r < 4; r++) {
    const int row = r0 + r;
    float M = -1e30f;
    for (int s = 0; s < NS; s++)
      M = fmaxf(M, ML[((size_t)s * NPTS + row) * 2]);
    float L = 0.0f, a = 0.0f;
    for (int s = 0; s < NS; s++) {
      float ms = ML[((size_t)s * NPTS + row) * 2];
      float ls = ML[((size_t)s * NPTS + row) * 2 + 1];
      float wsc = fexp2(ms - M);
      L += wsc * ls;
      a = fmaf(wsc, Opart[((size_t)s * NPTS + row) * CH + j], a);
    }
    xs[r][j] = a / L;
  }
  __syncthreads();

  // ---- GEMM + residual + LN ----
  float acc[4];
  const float bj = b[j];
  #pragma unroll
  for (int r = 0; r < 4; r++) acc[r] = bj;
  for (int kk = 0; kk < CH; kk++) {
    float wv_ = W[kk * CH + j];
    #pragma unroll
    for (int r = 0; r < 4; r++) acc[r] = fmaf(xs[r][kk], wv_, acc[r]);
  }
  #pragma unroll
  for (int r = 0; r < 4; r++) acc[r] += res[(r0 + r) * CH + j];

  const int wv2 = j >> 6, ln = j & 63;
  float sum[4];
  #pragma unroll
  for (int r = 0; r < 4; r++) sum[r] = acc[r];
  #pragma unroll
  for (int o = 32; o; o >>= 1) {
    #pragma unroll
    for (int r = 0; r < 4; r++) sum[r] += __shfl_xor(sum[r], o);
  }
  if (ln == 0) {
    #pragma unroll
    for (int r = 0; r < 4; r++) red[wv2][r] = sum[r];
  }
  __syncthreads();
  float dv[4];
  #pragma unroll
  for (int r = 0; r < 4; r++) {
    float mean = (red[0][r] + red[1][r]) * (1.0f / 128.0f);
    dv[r] = acc[r] - mean;
    sum[r] = dv[r] * dv[r];
  }
  #pragma unroll
  for (int o = 32; o; o >>= 1) {
    #pragma unroll
    for (int r = 0; r < 4; r++) sum[r] += __shfl_xor(sum[r], o);
  }
  __syncthreads();
  if (ln == 0) {
    #pragma unroll
    for (int r = 0; r < 4; r++) red[wv2][r] = sum[r];
  }
  __syncthreads();
  const float gj = g[j], betaj = beta[j];
  #pragma unroll
  for (int r = 0; r < 4; r++) {
    float var = (red[0][r] + red[1][r]) * (1.0f / 128.0f);
    out[(r0 + r) * CH + j] = dv[r] * rsqrtf(var + 1e-5f) * gj + betaj;
  }
}

// ---------------------------------------------------------------------------
// Kernel 5: final row normalize + classifier MLP + sigmoid
// ---------------------------------------------------------------------------
__global__ __launch_bounds__(128) void k_final(
    const float* __restrict__ F,
    const float* __restrict__ c1W, const float* __restrict__ c1b,
    const float* __restrict__ c2W, const float* __restrict__ c2b,
    const float* __restrict__ c3W, const float* __restrict__ c3b,
    float* __restrict__ out) {
  const int row = blockIdx.x, j = threadIdx.x;
  __shared__ float xs[CH];
  __shared__ float h1[32];
  __shared__ float h2[32];
  __shared__ float red[2];
  float x = F[row * CH + j];
  float ss = x * x;
  #pragma unroll
  for (int o = 32; o; o >>= 1) ss += __shfl_xor(ss, o);
  if ((j & 63) == 0) red[j >> 6] = ss;
  __syncthreads();
  float norm = sqrtf(red[0] + red[1]);
  float xn = x / fmaxf(norm, 1e-12f);
  xs[j] = xn;
  out[row * CH + j] = xn;
  __syncthreads();
  if (j < 32) {
    float a = c1b[j];
    for (int kk = 0; kk < CH; kk++) a = fmaf(xs[kk], c1W[kk * 32 + j], a);
    h1[j] = fmaxf(a, 0.0f);
  }
  __syncthreads();
  if (j < 32) {
    float a = c2b[j];
    #pragma unroll
    for (int kk = 0; kk < 32; kk++) a = fmaf(h1[kk], c2W[kk * 32 + j], a);
    h2[j] = fmaxf(a, 0.0f);
  }
  __syncthreads();
  if (j == 0) {
    float a = c3b[0];
    #pragma unroll
    for (int kk = 0; kk < 32; kk++) a = fmaf(h2[kk], c3W[kk], a);
    out[NPTS * CH + row] = 1.0f / (1.0f + __expf(-a));
  }
}

// ---------------------------------------------------------------------------
extern "C" void kernel_launch(void* const* d_in, const int* in_sizes, int n_in,
                              void* d_out, int out_size, void* d_ws, size_t ws_size,
                              hipStream_t stream) {
  const float* refp = (const float*)d_in[0];
  const float* srcp = (const float*)d_in[1];
  const float* cf   = (const float*)d_in[2];
  const float* Win  = (const float*)d_in[3];
  const float* bin  = (const float*)d_in[4];
  const float* mlpW = (const float*)d_in[5];
  const float* mlpb = (const float*)d_in[6];
  const float* mlpg = (const float*)d_in[7];
  const float* mlpbeta = (const float*)d_in[8];
  const float* Wq = (const float*)d_in[9];
  const float* bq = (const float*)d_in[10];
  const float* Wk = (const float*)d_in[11];
  const float* bk = (const float*)d_in[12];
  const float* Wv = (const float*)d_in[13];
  const float* bv = (const float*)d_in[14];
  const float* Wo = (const float*)d_in[15];
  const float* bo = (const float*)d_in[16];
  const float* lng = (const float*)d_in[17];
  const float* lnb = (const float*)d_in[18];
  const float* c1W = (const float*)d_in[19];
  const float* c1b = (const float*)d_in[20];
  const float* c2W = (const float*)d_in[21];
  const float* c2b = (const float*)d_in[22];
  const float* c3W = (const float*)d_in[23];
  const float* c3b = (const float*)d_in[24];
  float* out = (float*)d_out;

  const size_t NC = (size_t)NPTS * CH;
  float* F = (float*)d_ws;
  float* T = F + NC;
  ushort* Qb  = (ushort*)(T + NC);
  ushort* Kb  = Qb + NC;
  ushort* Vtb = Kb + NC;
  float* Opart = (float*)(Vtb + NC);

  // pick largest KV-split that fits the workspace
  const size_t base_bytes = 2 * NC * 4 + 3 * NC * 2;
  int NS = 1;
  for (int cand = 16; cand >= 2; cand >>= 1) {
    size_t need = base_bytes + (size_t)cand * (NC * 4 + NPTS * 8);
    if (need <= ws_size) { NS = cand; break; }
  }
  float* ML = Opart + (size_t)NS * NC;
  const int ntiles = NPTS / 64 / NS;

  k_embed<<<NPTS, 128, 0, stream>>>(refp, srcp, cf, Win, bin, F);
  for (int i = 0; i < 3; i++) {
    const int o2 = i * CH * CH, o1 = i * CH;
    k_mlp_qkv<<<NPTS / 4, 128, 0, stream>>>(
        F, mlpW + o2, mlpb + o1, mlpg + o1, mlpbeta + o1,
        Wq + o2, bq + o1, Wk + o2, bk + o1, Wv + o2, bv + o1,
        T, Qb, Kb, Vtb);
    dim3 agrid(NPTS / 128, NS);
    k_attn_mfma<<<agrid, 512, 0, stream>>>(Qb, Kb, Vtb, refp, srcp, Opart, ML, ntiles);
    k_out<<<NPTS / 4, 128, 0, stream>>>(Opart, ML, NS, Wo + o2, bo + o1,
                                        lng + o1, lnb + o1, T, F);
  }
  k_final<<<NPTS, 128, 0, stream>>>(F, c1W, c1b, c2W, c2b, c3W, c3b, out);
}